// Round 5
// baseline (221.918 us; speedup 1.0000x reference)
//
#include <hip/hip_runtime.h>
#include <hip/hip_bf16.h>

#define DD 256
#define BB 2048
#define BM 128                   // c3 rows per block tile
#define BN 64                    // batch columns per pipeline stage
#define NTILE ((DD * DD) / BM)   // 512 blocks
#define NSTAGE (BB / BN)         // 32 pipeline iterations

typedef __bf16 bf16x8 __attribute__((ext_vector_type(8)));
typedef float  f32x4  __attribute__((ext_vector_type(4)));

#define AS1 __attribute__((address_space(1)))
#define AS3 __attribute__((address_space(3)))

__device__ __forceinline__ unsigned short f2bf(float f) {
    unsigned int u = __float_as_uint(f);
    return (unsigned short)((u + 0x7FFFu + ((u >> 16) & 1u)) >> 16);  // RNE
}
__device__ __forceinline__ float bf2f(unsigned short s) {
    return __uint_as_float(((unsigned int)s) << 16);
}
__device__ __forceinline__ void async_cp16(const void* g, void* l) {
    __builtin_amdgcn_global_load_lds((const AS1 unsigned int*)g,
                                     (AS3 unsigned int*)l, 16, 0, 0);
}

// K1: fused rel = x - offsets (fp32 + bf16) and out[b] = c0 + <c1, rel_b>
__global__ void prep_all(const float* __restrict__ x, const float* __restrict__ offsets,
                         const float* __restrict__ c0, const float* __restrict__ c1,
                         float* __restrict__ rel_f32, unsigned short* __restrict__ rel_bf16,
                         float* __restrict__ out) {
    const int tid = threadIdx.x, wave = tid >> 6, lane = tid & 63;
    const float4 o4  = *(const float4*)(offsets + lane * 4);
    const float4 c14 = *(const float4*)(c1 + lane * 4);
#pragma unroll
    for (int i = 0; i < 2; ++i) {
        const int b = blockIdx.x * 8 + wave * 2 + i;
        const float4 x4 = *(const float4*)(x + (size_t)b * DD + lane * 4);
        float4 r;
        r.x = x4.x - o4.x; r.y = x4.y - o4.y; r.z = x4.z - o4.z; r.w = x4.w - o4.w;
        *(float4*)(rel_f32 + (size_t)b * DD + lane * 4) = r;
        ushort4 rb;
        rb.x = f2bf(r.x); rb.y = f2bf(r.y); rb.z = f2bf(r.z); rb.w = f2bf(r.w);
        *(ushort4*)(rel_bf16 + (size_t)b * DD + lane * 4) = rb;
        float s = r.x * c14.x + r.y * c14.y + r.z * c14.z + r.w * c14.w;
        s += __shfl_xor(s, 1);  s += __shfl_xor(s, 2);  s += __shfl_xor(s, 4);
        s += __shfl_xor(s, 8);  s += __shfl_xor(s, 16); s += __shfl_xor(s, 32);
        if (lane == 0) out[b] = c0[0] + s;
    }
}

// K3: fused GEMM (c3 tile @ rel^T) + c2 fold (from LDS) + weighted column reduction.
// 512 threads = 8 waves: 4 row-slices (wm) x 2 col-halves (wn); wave = 32 rows x 32 cols.
__global__ __launch_bounds__(512, 4) void taylor3(
    const float* __restrict__ c3, const float* __restrict__ c2,
    const float* __restrict__ rel_f32, const unsigned short* __restrict__ rel_bf16,
    float* __restrict__ partial)
{
    __shared__ unsigned short Bs[2][BN * DD];   // 64 KB, double-buffered
    __shared__ float relI[BB];                  // 8 KB: rel[:, i_t]
    __shared__ float c2row[BM];                 // 512 B: c2[i_t, jbase..jbase+128)
    __shared__ float colsum[2][4][BN];          // 2 KB, double-buffered per-wm partials

    const int tile = blockIdx.x;
    const int i_t   = tile >> 1;
    const int jbase = (tile & 1) << 7;
    const int tid  = threadIdx.x;
    const int wave = tid >> 6;
    const int lane = tid & 63;
    const int wm = wave & 3, wn = wave >> 2;
    const int lrow = lane & 15, quad = lane >> 4;

    // stage rel[:, i_t] and the c2 row-slice into LDS (one-time)
#pragma unroll
    for (int k = 0; k < 4; ++k) {
        const int b = tid + k * 512;
        relI[b] = rel_f32[(size_t)b * DD + i_t];
    }
    if (tid < BM) c2row[tid] = c2[i_t * DD + jbase + tid];

    // ---- hoist A fragments (c3, 32 rows/wave x 256 k) to registers ----
    bf16x8 afr[8][2];
    {
        const float* abase = c3 + (size_t)tile * BM * DD;
#pragma unroll
        for (int mt = 0; mt < 2; ++mt) {
            const int row = wm * 32 + mt * 16 + lrow;
            const float* p = abase + (size_t)row * DD + quad * 8;
#pragma unroll
            for (int ks = 0; ks < 8; ++ks) {
                float4 f0 = *(const float4*)(p + ks * 32);
                float4 f1 = *(const float4*)(p + ks * 32 + 4);
                union { unsigned short u[8]; bf16x8 v; } cv;
                cv.u[0] = f2bf(f0.x); cv.u[1] = f2bf(f0.y);
                cv.u[2] = f2bf(f0.z); cv.u[3] = f2bf(f0.w);
                cv.u[4] = f2bf(f1.x); cv.u[5] = f2bf(f1.y);
                cv.u[6] = f2bf(f1.z); cv.u[7] = f2bf(f1.w);
                afr[ks][mt] = cv.v;
            }
        }
    }

    // ---- async stage: tile nb -> Bs[buf]; 4 rounds x 16 rows, swizzled granules ----
    auto stage = [&](int nb, int buf) {
        const int b0 = nb * BN;
#pragma unroll
        for (int c = 0; c < 4; ++c) {
            const int r0 = c * 16 + wave * 2;           // wave-uniform base row
            const int row = r0 + (lane >> 5);
            const int g = (lane & 31) ^ (row & 7);      // logical granule for this phys slot
            const unsigned short* src = rel_bf16 + (size_t)(b0 + row) * DD + g * 8;
            async_cp16(src, &Bs[buf][r0 * DD]);
        }
    };

    stage(0, 0);
    int prev_b0 = -1;

    for (int nb = 0; nb < NSTAGE; ++nb) {
        const int cur = nb & 1;
        const int b0 = nb * BN;
        __syncthreads();          // drains async loads of Bs[cur]; WAR-protects Bs[cur^1]
        if (nb + 1 < NSTAGE) stage(nb + 1, cur ^ 1);

        // combine previous iteration's colsum (parity cur^1) while MFMA work proceeds
        if (prev_b0 >= 0 && tid < BN) {
            const float v = colsum[cur ^ 1][0][tid] + colsum[cur ^ 1][1][tid]
                          + colsum[cur ^ 1][2][tid] + colsum[cur ^ 1][3][tid];
            partial[(size_t)tile * BB + prev_b0 + tid] = relI[prev_b0 + tid] * v;
        }

        f32x4 acc[2][2];
#pragma unroll
        for (int mt = 0; mt < 2; ++mt)
#pragma unroll
            for (int nt = 0; nt < 2; ++nt)
                acc[mt][nt] = (f32x4){0.f, 0.f, 0.f, 0.f};

        // ---- K-loop: 8 steps of 16x16x32 over Bs[cur] ----
#pragma unroll
        for (int ks = 0; ks < 8; ++ks) {
            bf16x8 bfr[2];
#pragma unroll
            for (int nt = 0; nt < 2; ++nt) {
                const int col = wn * 32 + nt * 16 + lrow;
                const int g = (ks * 4 + quad) ^ (col & 7);
                bfr[nt] = *(const bf16x8*)(&Bs[cur][col * DD + g * 8]);
            }
#pragma unroll
            for (int mt = 0; mt < 2; ++mt)
#pragma unroll
                for (int nt = 0; nt < 2; ++nt)
                    acc[mt][nt] = __builtin_amdgcn_mfma_f32_16x16x32_bf16(
                        afr[ks][mt], bfr[nt], acc[mt][nt], 0, 0, 0);
        }

        // ---- epilogue: s(col) = sum_rows (G + c2) * r[b, j(row)]; quad-reduce ----
        float sv[2];
#pragma unroll
        for (int nt = 0; nt < 2; ++nt) {
            const int col = wn * 32 + nt * 16 + lrow;
            float s = 0.f;
#pragma unroll
            for (int mt = 0; mt < 2; ++mt) {
                const int el = wm * 32 + mt * 16 + quad * 4;   // local j within tile (0..127)
                const int e  = jbase + el;                     // global j (0..255)
                const int g  = (e >> 3) ^ (col & 7);
                const ushort4 rj = *(const ushort4*)(&Bs[cur][col * DD + g * 8 + (e & 7)]);
                const float4 c2r = *(const float4*)(&c2row[el]);  // broadcast read
                s += (acc[mt][nt][0] + c2r.x) * bf2f(rj.x);
                s += (acc[mt][nt][1] + c2r.y) * bf2f(rj.y);
                s += (acc[mt][nt][2] + c2r.z) * bf2f(rj.z);
                s += (acc[mt][nt][3] + c2r.w) * bf2f(rj.w);
            }
            s += __shfl_xor(s, 16, 64);
            s += __shfl_xor(s, 32, 64);
            sv[nt] = s;
        }
        if (lane < 32) colsum[cur][wm][wn * 32 + lane] = sv[lane >> 4];
        prev_b0 = b0;
    }
    __syncthreads();
    if (tid < BN) {   // final combine, parity (NSTAGE-1)&1 = 1
        const float v = colsum[1][0][tid] + colsum[1][1][tid]
                      + colsum[1][2][tid] + colsum[1][3][tid];
        partial[(size_t)tile * BB + prev_b0 + tid] = relI[prev_b0 + tid] * v;
    }
}

// K4: out[b] += sum over 512 partial rows. 128 blocks x 256 threads.
__global__ void reduce_partial(const float* __restrict__ partial, float* __restrict__ out) {
    __shared__ f32x4 red[256];
    const int t = threadIdx.x;
    const int g = blockIdx.x * 4 + (t & 3);   // float4 column group (512 total)
    const int slice = t >> 2;                 // 64 row-slices of 8 rows
    f32x4 s = (f32x4){0.f, 0.f, 0.f, 0.f};
    for (int r = slice * 8; r < slice * 8 + 8; ++r)
        s += *(const f32x4*)(partial + (size_t)r * BB + g * 4);
    red[t] = s; __syncthreads();
    if (t < 128) red[t] += red[t + 128]; __syncthreads();
    if (t < 64)  red[t] += red[t + 64];  __syncthreads();
    if (t < 32)  red[t] += red[t + 32];  __syncthreads();
    if (t < 16)  red[t] += red[t + 16];  __syncthreads();
    if (t < 8)   red[t] += red[t + 8];   __syncthreads();
    if (t < 4) {
        const f32x4 v = red[t] + red[t + 4];
        float4* op = (float4*)(out + (size_t)(blockIdx.x * 4 + t) * 4);
        float4 o = *op;
        o.x += v[0]; o.y += v[1]; o.z += v[2]; o.w += v[3];
        *op = o;
    }
}

extern "C" void kernel_launch(void* const* d_in, const int* in_sizes, int n_in,
                              void* d_out, int out_size, void* d_ws, size_t ws_size,
                              hipStream_t stream) {
    const float* x       = (const float*)d_in[0];
    const float* offsets = (const float*)d_in[1];
    const float* c0      = (const float*)d_in[2];
    const float* c1      = (const float*)d_in[3];
    const float* c2      = (const float*)d_in[4];
    const float* c3      = (const float*)d_in[5];
    float* out = (float*)d_out;

    char* ws = (char*)d_ws;
    float* rel_f32 = (float*)ws;                                             // 2 MB
    unsigned short* rel_bf16 = (unsigned short*)(ws + (size_t)BB * DD * 4);  // 1 MB
    float* partial = (float*)(ws + (size_t)BB * DD * 6);                     // 4 MB (512 x 2048)

    prep_all<<<BB / 8, 256, 0, stream>>>(x, offsets, c0, c1, rel_f32, rel_bf16, out);
    taylor3<<<NTILE, 512, 0, stream>>>(c3, c2, rel_f32, rel_bf16, partial);
    reduce_partial<<<128, 256, 0, stream>>>(partial, out);
}

// Round 6
// 191.434 us; speedup vs baseline: 1.1592x; 1.1592x over previous
//
#include <hip/hip_runtime.h>
#include <hip/hip_bf16.h>

#define DD 256
#define BB 2048
#define BM 128                   // c3 rows per block tile
#define BN 64                    // batch columns per pipeline stage
#define NTILE ((DD * DD) / BM)   // 512 blocks
#define NSTAGE (BB / BN)         // 32 pipeline iterations

typedef __bf16 bf16x8 __attribute__((ext_vector_type(8)));
typedef float  f32x4  __attribute__((ext_vector_type(4)));

#define AS1 __attribute__((address_space(1)))
#define AS3 __attribute__((address_space(3)))

__device__ __forceinline__ unsigned short f2bf(float f) {
    unsigned int u = __float_as_uint(f);
    return (unsigned short)((u + 0x7FFFu + ((u >> 16) & 1u)) >> 16);  // RNE
}
__device__ __forceinline__ float bf2f(unsigned short s) {
    return __uint_as_float(((unsigned int)s) << 16);
}
__device__ __forceinline__ void async_cp16(const void* g, void* l) {
    __builtin_amdgcn_global_load_lds((const AS1 unsigned int*)g,
                                     (AS3 unsigned int*)l, 16, 0, 0);
}

// K1: fused rel = x - offsets (fp32 + bf16) and out[b] = c0 + <c1, rel_b>
__global__ void prep_all(const float* __restrict__ x, const float* __restrict__ offsets,
                         const float* __restrict__ c0, const float* __restrict__ c1,
                         float* __restrict__ rel_f32, unsigned short* __restrict__ rel_bf16,
                         float* __restrict__ out) {
    const int tid = threadIdx.x, wave = tid >> 6, lane = tid & 63;
    const float4 o4  = *(const float4*)(offsets + lane * 4);
    const float4 c14 = *(const float4*)(c1 + lane * 4);
#pragma unroll
    for (int i = 0; i < 2; ++i) {
        const int b = blockIdx.x * 8 + wave * 2 + i;
        const float4 x4 = *(const float4*)(x + (size_t)b * DD + lane * 4);
        float4 r;
        r.x = x4.x - o4.x; r.y = x4.y - o4.y; r.z = x4.z - o4.z; r.w = x4.w - o4.w;
        *(float4*)(rel_f32 + (size_t)b * DD + lane * 4) = r;
        ushort4 rb;
        rb.x = f2bf(r.x); rb.y = f2bf(r.y); rb.z = f2bf(r.z); rb.w = f2bf(r.w);
        *(ushort4*)(rel_bf16 + (size_t)b * DD + lane * 4) = rb;
        float s = r.x * c14.x + r.y * c14.y + r.z * c14.z + r.w * c14.w;
        s += __shfl_xor(s, 1);  s += __shfl_xor(s, 2);  s += __shfl_xor(s, 4);
        s += __shfl_xor(s, 8);  s += __shfl_xor(s, 16); s += __shfl_xor(s, 32);
        if (lane == 0) out[b] = c0[0] + s;
    }
}

// K3: fused GEMM (c3 tile @ rel^T) + c2 fold + weighted column reduction.
// 512 threads = 8 waves: 4 row-slices (wm, 32 rows) x 2 k-halves (wk, 128 k).
// Each wave: 32 rows x 64 cols x 128 k -> afr only 32 VGPRs (spill fix).
__global__ __launch_bounds__(512, 4) void taylor3(
    const float* __restrict__ c3, const float* __restrict__ c2,
    const float* __restrict__ rel_f32, const unsigned short* __restrict__ rel_bf16,
    float* __restrict__ partial)
{
    __shared__ unsigned short Bs[2][BN * DD];   // 64 KB, double-buffered
    __shared__ float relI[BB];                  // 8 KB: rel[:, i_t]
    __shared__ float c2row[BM];                 // 512 B: c2[i_t, jbase..jbase+128)
    __shared__ float colsum[2][8][BN];          // 4 KB, double-buffered per-wave partials

    const int tile = blockIdx.x;
    const int i_t   = tile >> 1;
    const int jbase = (tile & 1) << 7;
    const int tid  = threadIdx.x;
    const int wave = tid >> 6;
    const int lane = tid & 63;
    const int wm = wave & 3, wk = wave >> 2;
    const int lrow = lane & 15, quad = lane >> 4;

    // stage rel[:, i_t] and the c2 row-slice into LDS (one-time)
#pragma unroll
    for (int k = 0; k < 4; ++k) {
        const int b = tid + k * 512;
        relI[b] = rel_f32[(size_t)b * DD + i_t];
    }
    if (tid < BM) c2row[tid] = c2[i_t * DD + jbase + tid];

    // ---- hoist A fragments: 32 rows x own 128-k half -> 32 VGPRs ----
    bf16x8 afr[4][2];
    {
        const float* abase = c3 + (size_t)tile * BM * DD;
#pragma unroll
        for (int mt = 0; mt < 2; ++mt) {
            const int row = wm * 32 + mt * 16 + lrow;
            const float* p = abase + (size_t)row * DD + wk * 128 + quad * 8;
#pragma unroll
            for (int ks = 0; ks < 4; ++ks) {
                float4 f0 = *(const float4*)(p + ks * 32);
                float4 f1 = *(const float4*)(p + ks * 32 + 4);
                union { unsigned short u[8]; bf16x8 v; } cv;
                cv.u[0] = f2bf(f0.x); cv.u[1] = f2bf(f0.y);
                cv.u[2] = f2bf(f0.z); cv.u[3] = f2bf(f0.w);
                cv.u[4] = f2bf(f1.x); cv.u[5] = f2bf(f1.y);
                cv.u[6] = f2bf(f1.z); cv.u[7] = f2bf(f1.w);
                afr[ks][mt] = cv.v;
            }
        }
    }

    // ---- async stage: tile nb -> Bs[buf]; 4 rounds x 16 rows, swizzled granules ----
    auto stage = [&](int nb, int buf) {
        const int b0 = nb * BN;
#pragma unroll
        for (int c = 0; c < 4; ++c) {
            const int r0 = c * 16 + wave * 2;           // wave-uniform base row
            const int row = r0 + (lane >> 5);
            const int g = (lane & 31) ^ (row & 7);      // logical granule for this phys slot
            const unsigned short* src = rel_bf16 + (size_t)(b0 + row) * DD + g * 8;
            async_cp16(src, &Bs[buf][r0 * DD]);
        }
    };

    stage(0, 0);
    int prev_b0 = -1;

    for (int nb = 0; nb < NSTAGE; ++nb) {
        const int cur = nb & 1;
        const int b0 = nb * BN;
        __syncthreads();          // drains async loads of Bs[cur]; WAR-protects Bs[cur^1]
        if (nb + 1 < NSTAGE) stage(nb + 1, cur ^ 1);

        // combine previous iteration's colsum (parity cur^1) while MFMA work proceeds
        if (prev_b0 >= 0 && tid < BN) {
            float v = 0.f;
#pragma unroll
            for (int w = 0; w < 8; ++w) v += colsum[cur ^ 1][w][tid];
            partial[(size_t)tile * BB + prev_b0 + tid] = relI[prev_b0 + tid] * v;
        }

        f32x4 acc[2][4];
#pragma unroll
        for (int mt = 0; mt < 2; ++mt)
#pragma unroll
            for (int nt = 0; nt < 4; ++nt)
                acc[mt][nt] = (f32x4){0.f, 0.f, 0.f, 0.f};

        // ---- K-loop: 4 steps of 16x16x32 over this wave's 128-k half ----
#pragma unroll
        for (int ks = 0; ks < 4; ++ks) {
            const int glog = wk * 16 + ks * 4 + quad;   // logical granule of this k-chunk
            bf16x8 bfr[4];
#pragma unroll
            for (int nt = 0; nt < 4; ++nt) {
                const int col = nt * 16 + lrow;
                const int g = glog ^ (col & 7);
                bfr[nt] = *(const bf16x8*)(&Bs[cur][col * DD + g * 8]);
            }
#pragma unroll
            for (int mt = 0; mt < 2; ++mt)
#pragma unroll
                for (int nt = 0; nt < 4; ++nt)
                    acc[mt][nt] = __builtin_amdgcn_mfma_f32_16x16x32_bf16(
                        afr[ks][mt], bfr[nt], acc[mt][nt], 0, 0, 0);
        }

        // ---- epilogue: s(col) = sum_rows (G_half + c2?) * r[b, j(row)]; butterfly ----
        float sv[4];
#pragma unroll
        for (int nt = 0; nt < 4; ++nt) {
            const int col = nt * 16 + lrow;
            float s = 0.f;
#pragma unroll
            for (int mt = 0; mt < 2; ++mt) {
                const int el = wm * 32 + mt * 16 + quad * 4;   // local j (0..127)
                const int e  = jbase + el;                     // global j
                const int g  = (e >> 3) ^ (col & 7);
                const ushort4 rj = *(const ushort4*)(&Bs[cur][col * DD + g * 8 + (e & 7)]);
                float c2x = 0.f, c2y = 0.f, c2z = 0.f, c2w = 0.f;
                if (wk == 0) {   // c2 folded exactly once (wave-uniform branch)
                    const float4 c2r = *(const float4*)(&c2row[el]);
                    c2x = c2r.x; c2y = c2r.y; c2z = c2r.z; c2w = c2r.w;
                }
                s += (acc[mt][nt][0] + c2x) * bf2f(rj.x);
                s += (acc[mt][nt][1] + c2y) * bf2f(rj.y);
                s += (acc[mt][nt][2] + c2z) * bf2f(rj.z);
                s += (acc[mt][nt][3] + c2w) * bf2f(rj.w);
            }
            s += __shfl_xor(s, 16, 64);
            s += __shfl_xor(s, 32, 64);   // butterfly: all lanes hold the column total
            sv[nt] = s;
        }
        {   // lane L writes col L: sv[L>>4] (select, not dynamic index)
            const float v01 = (quad & 1) ? sv[1] : sv[0];
            const float v23 = (quad & 1) ? sv[3] : sv[2];
            colsum[cur][wave][lane] = (quad & 2) ? v23 : v01;
        }
        prev_b0 = b0;
    }
    __syncthreads();
    if (tid < BN) {   // final combine, parity (NSTAGE-1)&1 = 1
        float v = 0.f;
#pragma unroll
        for (int w = 0; w < 8; ++w) v += colsum[1][w][tid];
        partial[(size_t)tile * BB + prev_b0 + tid] = relI[prev_b0 + tid] * v;
    }
}

// K4: out[b] += sum over 512 partial rows. 128 blocks x 256 threads.
__global__ void reduce_partial(const float* __restrict__ partial, float* __restrict__ out) {
    __shared__ f32x4 red[256];
    const int t = threadIdx.x;
    const int g = blockIdx.x * 4 + (t & 3);   // float4 column group (512 total)
    const int slice = t >> 2;                 // 64 row-slices of 8 rows
    f32x4 s = (f32x4){0.f, 0.f, 0.f, 0.f};
    for (int r = slice * 8; r < slice * 8 + 8; ++r)
        s += *(const f32x4*)(partial + (size_t)r * BB + g * 4);
    red[t] = s; __syncthreads();
    if (t < 128) red[t] += red[t + 128]; __syncthreads();
    if (t < 64)  red[t] += red[t + 64];  __syncthreads();
    if (t < 32)  red[t] += red[t + 32];  __syncthreads();
    if (t < 16)  red[t] += red[t + 16];  __syncthreads();
    if (t < 8)   red[t] += red[t + 8];   __syncthreads();
    if (t < 4) {
        const f32x4 v = red[t] + red[t + 4];
        float4* op = (float4*)(out + (size_t)(blockIdx.x * 4 + t) * 4);
        float4 o = *op;
        o.x += v[0]; o.y += v[1]; o.z += v[2]; o.w += v[3];
        *op = o;
    }
}

extern "C" void kernel_launch(void* const* d_in, const int* in_sizes, int n_in,
                              void* d_out, int out_size, void* d_ws, size_t ws_size,
                              hipStream_t stream) {
    const float* x       = (const float*)d_in[0];
    const float* offsets = (const float*)d_in[1];
    const float* c0      = (const float*)d_in[2];
    const float* c1      = (const float*)d_in[3];
    const float* c2      = (const float*)d_in[4];
    const float* c3      = (const float*)d_in[5];
    float* out = (float*)d_out;

    char* ws = (char*)d_ws;
    float* rel_f32 = (float*)ws;                                             // 2 MB
    unsigned short* rel_bf16 = (unsigned short*)(ws + (size_t)BB * DD * 4);  // 1 MB
    float* partial = (float*)(ws + (size_t)BB * DD * 6);                     // 4 MB (512 x 2048)

    prep_all<<<BB / 8, 256, 0, stream>>>(x, offsets, c0, c1, rel_f32, rel_bf16, out);
    taylor3<<<NTILE, 512, 0, stream>>>(c3, c2, rel_f32, rel_bf16, partial);
    reduce_partial<<<128, 256, 0, stream>>>(partial, out);
}

// Round 7
// 188.584 us; speedup vs baseline: 1.1768x; 1.0151x over previous
//
#include <hip/hip_runtime.h>
#include <hip/hip_bf16.h>

#define DD 256
#define BB 2048
#define BM 128                   // c3 rows per block tile
#define BN 64                    // batch columns per pipeline stage
#define NTILE ((DD * DD) / BM)   // 512 blocks
#define NSTAGE (BB / BN)         // 32 pipeline iterations

typedef __bf16 bf16x8 __attribute__((ext_vector_type(8)));
typedef float  f32x4  __attribute__((ext_vector_type(4)));

#define AS1 __attribute__((address_space(1)))
#define AS3 __attribute__((address_space(3)))

__device__ __forceinline__ unsigned short f2bf(float f) {
    unsigned int u = __float_as_uint(f);
    return (unsigned short)((u + 0x7FFFu + ((u >> 16) & 1u)) >> 16);  // RNE
}
__device__ __forceinline__ float bf2f(unsigned short s) {
    return __uint_as_float(((unsigned int)s) << 16);
}
__device__ __forceinline__ void async_cp16(const void* g, void* l) {
    __builtin_amdgcn_global_load_lds((const AS1 unsigned int*)g,
                                     (AS3 unsigned int*)l, 16, 0, 0);
}

// K1: fused rel = x - offsets (fp32 + bf16) and out[b] = c0 + <c1, rel_b>
__global__ void prep_all(const float* __restrict__ x, const float* __restrict__ offsets,
                         const float* __restrict__ c0, const float* __restrict__ c1,
                         float* __restrict__ rel_f32, unsigned short* __restrict__ rel_bf16,
                         float* __restrict__ out) {
    const int tid = threadIdx.x, wave = tid >> 6, lane = tid & 63;
    const float4 o4  = *(const float4*)(offsets + lane * 4);
    const float4 c14 = *(const float4*)(c1 + lane * 4);
#pragma unroll
    for (int i = 0; i < 2; ++i) {
        const int b = blockIdx.x * 8 + wave * 2 + i;
        const float4 x4 = *(const float4*)(x + (size_t)b * DD + lane * 4);
        float4 r;
        r.x = x4.x - o4.x; r.y = x4.y - o4.y; r.z = x4.z - o4.z; r.w = x4.w - o4.w;
        *(float4*)(rel_f32 + (size_t)b * DD + lane * 4) = r;
        ushort4 rb;
        rb.x = f2bf(r.x); rb.y = f2bf(r.y); rb.z = f2bf(r.z); rb.w = f2bf(r.w);
        *(ushort4*)(rel_bf16 + (size_t)b * DD + lane * 4) = rb;
        float s = r.x * c14.x + r.y * c14.y + r.z * c14.z + r.w * c14.w;
        s += __shfl_xor(s, 1);  s += __shfl_xor(s, 2);  s += __shfl_xor(s, 4);
        s += __shfl_xor(s, 8);  s += __shfl_xor(s, 16); s += __shfl_xor(s, 32);
        if (lane == 0) out[b] = c0[0] + s;
    }
}

// K3: fused GEMM (c3 tile @ rel^T) + c2 fold + weighted column reduction.
// 256 threads = 4 waves: 2 row-halves (wm, 64 rows via mt=4) x 2 k-halves (wk, 128 k).
// 2 waves/SIMD (LDS-capped) -> 256-reg budget: afr 64 + acc 64 fits, no spill.
__global__ __launch_bounds__(256, 2) void taylor3(
    const float* __restrict__ c3, const float* __restrict__ c2,
    const float* __restrict__ rel_f32, const unsigned short* __restrict__ rel_bf16,
    float* __restrict__ partial)
{
    __shared__ unsigned short Bs[2][BN * DD];   // 64 KB, double-buffered
    __shared__ float relI[BB];                  // 8 KB: rel[:, i_t]
    __shared__ float c2row[BM];                 // 512 B: c2[i_t, jbase..jbase+128)
    __shared__ float colsum[2][4][BN];          // 2 KB, double-buffered per-wave partials

    const int tile = blockIdx.x;
    const int i_t   = tile >> 1;
    const int jbase = (tile & 1) << 7;
    const int tid  = threadIdx.x;
    const int wave = tid >> 6;
    const int lane = tid & 63;
    const int wm = wave & 1, wk = wave >> 1;
    const int lrow = lane & 15, quad = lane >> 4;

    // stage rel[:, i_t] and the c2 row-slice into LDS (one-time)
#pragma unroll
    for (int k = 0; k < 8; ++k) {
        const int b = tid + k * 256;
        relI[b] = rel_f32[(size_t)b * DD + i_t];
    }
    if (tid < BM) c2row[tid] = c2[i_t * DD + jbase + tid];

    // ---- hoist A fragments: 64 rows (mt=4) x own 128-k half -> 64 VGPRs ----
    bf16x8 afr[4][4];
    {
        const float* abase = c3 + (size_t)tile * BM * DD;
#pragma unroll
        for (int mt = 0; mt < 4; ++mt) {
            const int row = wm * 64 + mt * 16 + lrow;
            const float* p = abase + (size_t)row * DD + wk * 128 + quad * 8;
#pragma unroll
            for (int ks = 0; ks < 4; ++ks) {
                float4 f0 = *(const float4*)(p + ks * 32);
                float4 f1 = *(const float4*)(p + ks * 32 + 4);
                union { unsigned short u[8]; bf16x8 v; } cv;
                cv.u[0] = f2bf(f0.x); cv.u[1] = f2bf(f0.y);
                cv.u[2] = f2bf(f0.z); cv.u[3] = f2bf(f0.w);
                cv.u[4] = f2bf(f1.x); cv.u[5] = f2bf(f1.y);
                cv.u[6] = f2bf(f1.z); cv.u[7] = f2bf(f1.w);
                afr[ks][mt] = cv.v;
            }
        }
    }

    // ---- async stage: tile nb -> Bs[buf]; 8 rounds x 8 rows, swizzled granules ----
    auto stage = [&](int nb, int buf) {
        const int b0 = nb * BN;
#pragma unroll
        for (int c = 0; c < 8; ++c) {
            const int r0 = c * 8 + wave * 2;            // wave-uniform base row
            const int row = r0 + (lane >> 5);
            const int g = (lane & 31) ^ (row & 7);      // logical granule for this phys slot
            const unsigned short* src = rel_bf16 + (size_t)(b0 + row) * DD + g * 8;
            async_cp16(src, &Bs[buf][r0 * DD]);
        }
    };

    stage(0, 0);
    int prev_b0 = -1;

    for (int nb = 0; nb < NSTAGE; ++nb) {
        const int cur = nb & 1;
        const int b0 = nb * BN;
        __syncthreads();          // drains async loads of Bs[cur]; WAR-protects Bs[cur^1]
        if (nb + 1 < NSTAGE) stage(nb + 1, cur ^ 1);

        // combine previous iteration's colsum (parity cur^1) while MFMA work proceeds
        if (prev_b0 >= 0 && tid < BN) {
            const float v = colsum[cur ^ 1][0][tid] + colsum[cur ^ 1][1][tid]
                          + colsum[cur ^ 1][2][tid] + colsum[cur ^ 1][3][tid];
            partial[(size_t)tile * BB + prev_b0 + tid] = relI[prev_b0 + tid] * v;
        }

        f32x4 acc[4][4];
#pragma unroll
        for (int mt = 0; mt < 4; ++mt)
#pragma unroll
            for (int nt = 0; nt < 4; ++nt)
                acc[mt][nt] = (f32x4){0.f, 0.f, 0.f, 0.f};

        // ---- K-loop: 4 steps of 16x16x32 over this wave's 128-k half ----
#pragma unroll
        for (int ks = 0; ks < 4; ++ks) {
            const int glog = wk * 16 + ks * 4 + quad;   // logical granule of this k-chunk
            bf16x8 bfr[4];
#pragma unroll
            for (int nt = 0; nt < 4; ++nt) {
                const int col = nt * 16 + lrow;
                const int g = glog ^ (col & 7);
                bfr[nt] = *(const bf16x8*)(&Bs[cur][col * DD + g * 8]);
            }
#pragma unroll
            for (int mt = 0; mt < 4; ++mt)
#pragma unroll
                for (int nt = 0; nt < 4; ++nt)
                    acc[mt][nt] = __builtin_amdgcn_mfma_f32_16x16x32_bf16(
                        afr[ks][mt], bfr[nt], acc[mt][nt], 0, 0, 0);
        }

        // ---- epilogue: s(col) = sum_rows (G_half + c2?) * r[b, j(row)]; butterfly ----
        float sv[4];
#pragma unroll
        for (int nt = 0; nt < 4; ++nt) {
            const int col = nt * 16 + lrow;
            float s = 0.f;
#pragma unroll
            for (int mt = 0; mt < 4; ++mt) {
                const int el = wm * 64 + mt * 16 + quad * 4;   // local j (0..127)
                const int e  = jbase + el;                     // global j
                const int g  = (e >> 3) ^ (col & 7);
                const ushort4 rj = *(const ushort4*)(&Bs[cur][col * DD + g * 8 + (e & 7)]);
                float c2x = 0.f, c2y = 0.f, c2z = 0.f, c2w = 0.f;
                if (wk == 0) {   // c2 folded exactly once (wave-uniform branch)
                    const float4 c2r = *(const float4*)(&c2row[el]);
                    c2x = c2r.x; c2y = c2r.y; c2z = c2r.z; c2w = c2r.w;
                }
                s += (acc[mt][nt][0] + c2x) * bf2f(rj.x);
                s += (acc[mt][nt][1] + c2y) * bf2f(rj.y);
                s += (acc[mt][nt][2] + c2z) * bf2f(rj.z);
                s += (acc[mt][nt][3] + c2w) * bf2f(rj.w);
            }
            s += __shfl_xor(s, 16, 64);
            s += __shfl_xor(s, 32, 64);   // butterfly: all lanes hold the column total
            sv[nt] = s;
        }
        {   // lane L writes col L: sv[L>>4] (select, not dynamic index)
            const float v01 = (quad & 1) ? sv[1] : sv[0];
            const float v23 = (quad & 1) ? sv[3] : sv[2];
            colsum[cur][wave][lane] = (quad & 2) ? v23 : v01;
        }
        prev_b0 = b0;
    }
    __syncthreads();
    if (tid < BN) {   // final combine, parity (NSTAGE-1)&1 = 1
        const float v = colsum[1][0][tid] + colsum[1][1][tid]
                      + colsum[1][2][tid] + colsum[1][3][tid];
        partial[(size_t)tile * BB + prev_b0 + tid] = relI[prev_b0 + tid] * v;
    }
}

// K4: out[b] += sum over 512 partial rows. 128 blocks x 256 threads.
__global__ void reduce_partial(const float* __restrict__ partial, float* __restrict__ out) {
    __shared__ f32x4 red[256];
    const int t = threadIdx.x;
    const int g = blockIdx.x * 4 + (t & 3);   // float4 column group (512 total)
    const int slice = t >> 2;                 // 64 row-slices of 8 rows
    f32x4 s = (f32x4){0.f, 0.f, 0.f, 0.f};
    for (int r = slice * 8; r < slice * 8 + 8; ++r)
        s += *(const f32x4*)(partial + (size_t)r * BB + g * 4);
    red[t] = s; __syncthreads();
    if (t < 128) red[t] += red[t + 128]; __syncthreads();
    if (t < 64)  red[t] += red[t + 64];  __syncthreads();
    if (t < 32)  red[t] += red[t + 32];  __syncthreads();
    if (t < 16)  red[t] += red[t + 16];  __syncthreads();
    if (t < 8)   red[t] += red[t + 8];   __syncthreads();
    if (t < 4) {
        const f32x4 v = red[t] + red[t + 4];
        float4* op = (float4*)(out + (size_t)(blockIdx.x * 4 + t) * 4);
        float4 o = *op;
        o.x += v[0]; o.y += v[1]; o.z += v[2]; o.w += v[3];
        *op = o;
    }
}

extern "C" void kernel_launch(void* const* d_in, const int* in_sizes, int n_in,
                              void* d_out, int out_size, void* d_ws, size_t ws_size,
                              hipStream_t stream) {
    const float* x       = (const float*)d_in[0];
    const float* offsets = (const float*)d_in[1];
    const float* c0      = (const float*)d_in[2];
    const float* c1      = (const float*)d_in[3];
    const float* c2      = (const float*)d_in[4];
    const float* c3      = (const float*)d_in[5];
    float* out = (float*)d_out;

    char* ws = (char*)d_ws;
    float* rel_f32 = (float*)ws;                                             // 2 MB
    unsigned short* rel_bf16 = (unsigned short*)(ws + (size_t)BB * DD * 4);  // 1 MB
    float* partial = (float*)(ws + (size_t)BB * DD * 6);                     // 4 MB (512 x 2048)

    prep_all<<<BB / 8, 256, 0, stream>>>(x, offsets, c0, c1, rel_f32, rel_bf16, out);
    taylor3<<<NTILE, 256, 0, stream>>>(c3, c2, rel_f32, rel_bf16, partial);
    reduce_partial<<<128, 256, 0, stream>>>(partial, out);
}